// Round 17
// baseline (165.178 us; speedup 1.0000x reference)
//
#include <hip/hip_runtime.h>
#include <hip/hip_bf16.h>

#define NN 10000
#define NE 320000
#define CAP 96   // deg ~ Binom(320000,1e-4): mean 32, sd 5.66; P(overflow) < 1e-19

typedef __attribute__((ext_vector_type(8)))  __bf16 bf16x8;
typedef __attribute__((ext_vector_type(16))) float  f32x16;
typedef __attribute__((ext_vector_type(4)))  float  f32x4;

// ======================= bucket scatter + W->bf16 prep =======================
// blocks 0..639: group edges by dst. block 640: convert W to bf16 in the
// af-fragment layout: wbf[g*512 + hi*256 + c*8 + j] = W[(hi*8+j)*1024 + g*32 + c].
// wbf is 32KB == one CU's L1: after warmup every af read is an L1/L2 hit (r13
// proved global-W is neutral vs LDS-W at equal occupancy).
__global__ void scatter_bucket_kernel(const int* __restrict__ eidx,
                                      int* __restrict__ cnt, int2* __restrict__ bucket,
                                      const float* __restrict__ W, __bf16* __restrict__ wbf) {
    if (blockIdx.x == 640) {
        for (int u = threadIdx.x; u < 16384; u += 256) {
            int j = u & 7, c = (u >> 3) & 31, hi = (u >> 8) & 1, g = u >> 9;
            wbf[u] = (__bf16)W[(hi * 8 + j) * 1024 + g * 32 + c];
        }
        return;
    }
    for (int e = blockIdx.x * 256 + threadIdx.x; e < NE; e += 640 * 256) {
        int d = eidx[NE + e];
        int s = eidx[e];
        int p = atomicAdd(&cnt[d], 1);
        if (p < CAP) bucket[d * CAP + p] = make_int2(e, s);
    }
}

// ======================= 1-wave-per-node fused edge + epilogue kernel =======================
// r17 structural change: 64-thread blocks, grid = NN. r7-r16 ledger: VALU-busy
// ~40us invariant, occupancy pinned ~27% in EVERY 256-thread config -- 2500
// blocks x 4-wave straggler coupling (deg varies per wave) + ramp/tail. One
// wave per block decouples nodes; LDS ~8.5KB (W in global/L1 per r13) so
// residency is VGPR-bound: (64,6) = 85-reg budget, 6 waves/SIMD.
//
// SPILL TRAP (r5/r6, 0.7-2.7 GB scratch): opaque base per chunk so af/ci
// reads can't be hoisted chunk-invariantly; sched_barrier(0) every 2nd group
// (r10-proven best: 2 acc tiles live).
// VGPR BUDGET (r14 lesson): bound from computed liveness (~64, r13-measured),
// budget 85.
__global__ __launch_bounds__(64, 6) void edge_node_kernel(
    const float* __restrict__ x, const float* __restrict__ ea,
    const __bf16* __restrict__ wbf, const float* __restrict__ be,
    const float* __restrict__ root, const float* __restrict__ bias,
    const int* __restrict__ cnt, const int2* __restrict__ bucket,
    float* __restrict__ out)
{
    __shared__ __attribute__((aligned(16))) float BPF[32][2][16];   // 4 KiB permuted bias
    __shared__ __attribute__((aligned(16))) float root_s[32][32];   // 4 KiB
    __shared__ float bias_s[32];
    __shared__ float msum[32];

    const int tid = threadIdx.x;    // 0..63, single wave

    #pragma unroll
    for (int k = 0; k < 16; ++k) {
        int idx = tid + k * 64;               // 1024 entries
        int cb = idx >> 5, rem = idx & 31, hi2 = rem >> 4, r = rem & 15;
        int row = (r & 3) + 8 * (r >> 2) + 4 * hi2;
        BPF[cb][hi2][r] = be[cb * 32 + row];
        root_s[idx >> 5][idx & 31] = root[idx];
    }
    if (tid < 32) bias_s[tid] = bias[tid];
    __syncthreads();

    const int hi  = tid >> 5;
    const int l31 = tid & 31;
    const int n   = blockIdx.x;               // one node per block

    const int deg = cnt[n];
    const int2* bk = bucket + (size_t)n * CAP;
    const __bf16* wb = wbf + hi * 256 + (size_t)l31 * 8;   // + g*512 per group

    float msgr[16];
    #pragma unroll
    for (int r = 0; r < 16; ++r) msgr[r] = 0.0f;

    for (int c0 = 0; c0 < deg; c0 += 32) {
        const int idx  = c0 + l31;
        const bool act = idx < deg;
        const int2 es  = bk[act ? idx : deg - 1];

        const f32x4* eap = (const f32x4*)(ea + (size_t)es.x * 16 + hi * 8);
        f32x4 f0 = eap[0];
        f32x4 f1 = eap[1];
        bf16x8 bfrag;
        bfrag[0]=(__bf16)f0.x; bfrag[1]=(__bf16)f0.y; bfrag[2]=(__bf16)f0.z; bfrag[3]=(__bf16)f0.w;
        bfrag[4]=(__bf16)f1.x; bfrag[5]=(__bf16)f1.y; bfrag[6]=(__bf16)f1.z; bfrag[7]=(__bf16)f1.w;

        const f32x4* xp = (const f32x4*)(x + (size_t)es.y * 32);

        // opaque base: defeats LICM/CSE of the af/ci reads across chunks.
        int base = 0;
        asm volatile("" : "+v"(base));

        #pragma unroll
        for (int cbq = 0; cbq < 8; ++cbq) {
            f32x4 xq = xp[cbq];
            if (!act) { xq.x = 0.f; xq.y = 0.f; xq.z = 0.f; xq.w = 0.f; }
            #pragma unroll
            for (int c4 = 0; c4 < 4; ++c4) {
                const int g = cbq * 4 + c4;
                bf16x8 af = *(const bf16x8*)(wb + (size_t)(base + g) * 512);
                f32x16 ci = *(const f32x16*)(&BPF[base + g][hi][0]);
                f32x16 acc = __builtin_amdgcn_mfma_f32_32x32x16_bf16(af, bfrag, ci, 0, 0, 0);
                const float xv = (c4 == 0) ? xq.x : (c4 == 1) ? xq.y : (c4 == 2) ? xq.z : xq.w;
                #pragma unroll
                for (int r = 0; r < 16; ++r)
                    msgr[r] += fmaxf(acc[r], 0.0f) * xv;
                if (c4 & 1) __builtin_amdgcn_sched_barrier(0);  // 2-group window (r10)
            }
        }
    }

    // reduce across the 32 slot-lanes within each hi-half
    #pragma unroll
    for (int m = 1; m <= 16; m <<= 1) {
        #pragma unroll
        for (int r = 0; r < 16; ++r)
            msgr[r] += __shfl_xor(msgr[r], m, 64);
    }

    const float rdeg = (deg > 0) ? (1.0f / (float)deg) : 0.0f;
    if (l31 == 0) {
        #pragma unroll
        for (int r = 0; r < 16; ++r) {
            const int o = (r & 3) + 8 * (r >> 2) + 4 * hi;
            msum[o] = msgr[r] * rdeg;
        }
    }
    __syncthreads();

    // epilogue: out[n][o] = mean_msg[o] + bias[o] + sum_i x[n][i]*root[i][o]
    const float xv = x[(size_t)n * 32 + l31];
    if (hi == 0) {
        float m = msum[l31] + bias_s[l31];
        #pragma unroll
        for (int i = 0; i < 32; ++i)
            m += __shfl(xv, i, 64) * root_s[i][l31];
        out[(size_t)n * 32 + l31] = m;
    }
}

// ======================= launch =======================
extern "C" void kernel_launch(void* const* d_in, const int* in_sizes, int n_in,
                              void* d_out, int out_size, void* d_ws, size_t ws_size,
                              hipStream_t stream) {
    const float* x    = (const float*)d_in[0];
    const int*   eidx = (const int*)d_in[1];     // [2][NE]
    const float* ea   = (const float*)d_in[2];   // [NE][16]
    const float* W    = (const float*)d_in[3];   // [16][1024]
    const float* be   = (const float*)d_in[4];   // [1024]
    const float* root = (const float*)d_in[5];   // [32][32]
    const float* bias = (const float*)d_in[6];   // [32]
    float* out = (float*)d_out;

    // ws: cnt[NN] ints | bucket int2[NN*CAP] | wbf bf16[16384]
    int*    cnt    = (int*)d_ws;
    int2*   bucket = (int2*)((char*)d_ws + 40000);
    __bf16* wbf    = (__bf16*)((char*)d_ws + 40000 + (size_t)NN * CAP * 8);

    hipMemsetAsync(cnt, 0, NN * sizeof(int), stream);
    scatter_bucket_kernel<<<641, 256, 0, stream>>>(eidx, cnt, bucket, W, wbf);
    edge_node_kernel<<<NN, 64, 0, stream>>>(x, ea, wbf, be, root, bias,
                                            cnt, bucket, out);
}

// Round 18
// 100.490 us; speedup vs baseline: 1.6437x; 1.6437x over previous
//
#include <hip/hip_runtime.h>
#include <hip/hip_bf16.h>

#define NN 10000
#define NE 320000
#define CAP 96   // deg ~ Binom(320000,1e-4): mean 32, sd 5.66; P(overflow) < 1e-19

typedef __attribute__((ext_vector_type(8)))  __bf16 bf16x8;
typedef __attribute__((ext_vector_type(16))) float  f32x16;
typedef __attribute__((ext_vector_type(4)))  float  f32x4;

// ======================= bucket scatter =======================
__global__ void scatter_bucket_kernel(const int* __restrict__ eidx,
                                      int* __restrict__ cnt, int2* __restrict__ bucket) {
    for (int e = blockIdx.x * 256 + threadIdx.x; e < NE; e += gridDim.x * 256) {
        int d = eidx[NE + e];
        int s = eidx[e];
        int p = atomicAdd(&cnt[d], 1);
        if (p < CAP) bucket[d * CAP + p] = make_int2(e, s);
    }
}

// ======================= node-centric fused edge + epilogue kernel =======================
// r18 = r11 (best measured: edge 77us, total 100.2us) + 2 SEQUENTIAL nodes per
// wave (grid NN/8): halves the per-block W-staging overhead (32KB stage paid
// 1250x not 2500x, ~12-15% of edge VALU) with IDENTICAL inner-loop liveness
// (sequential reuse of msgr/acc, unlike r14/r15 parallel streams which needed
// 128 regs). Node0's reduce/store latency overlaps node1's first chunk.
//
// SPILL TRAP (r5/r6, 0.7-2.7 GB scratch): opaque base per chunk so af/ci LDS
// reads can't be hoisted chunk-invariantly; sched_barrier(0) every 2nd group
// (r10-proven: 2 acc tiles live, 64-68 VGPR).
// OCCUPANCY (r8/r9/r14/r17 lessons): (256,3); stronger caps either spill
// (bound < liveness) or don't bind.
__global__ __launch_bounds__(256, 3) void edge_node_kernel(
    const float* __restrict__ x, const float* __restrict__ ea,
    const float* __restrict__ W, const float* __restrict__ be,
    const float* __restrict__ root, const float* __restrict__ bias,
    const int* __restrict__ cnt, const int2* __restrict__ bucket,
    float* __restrict__ out)
{
    __shared__ __attribute__((aligned(16))) __bf16 WT[32][2][32][8];  // 32 KiB
    __shared__ __attribute__((aligned(16))) float  BPF[32][2][16];    // 4 KiB
    __shared__ __attribute__((aligned(16))) float  root_s[32][32];    // 4 KiB
    __shared__ float bias_s[32];
    __shared__ float msum[8][32];

    const int tid = threadIdx.x;

    #pragma unroll
    for (int k = 0; k < 8; ++k) {
        int idx = tid + k * 256;              // (cb, hi, c)
        int cb = idx >> 6, rem = idx & 63, hi2 = rem >> 5, c = rem & 31;
        int cg = cb * 32 + c;
        #pragma unroll
        for (int j = 0; j < 8; ++j)
            WT[cb][hi2][c][j] = (__bf16)W[(8 * hi2 + j) * 1024 + cg];
    }
    #pragma unroll
    for (int k = 0; k < 4; ++k) {
        int idx = tid + k * 256;              // (cb, hi, r) + root staging
        int cb = idx >> 5, rem = idx & 31, hi2 = rem >> 4, r = rem & 15;
        int row = (r & 3) + 8 * (r >> 2) + 4 * hi2;
        BPF[cb][hi2][r] = be[cb * 32 + row];
        root_s[idx >> 5][idx & 31] = root[idx];
    }
    if (tid < 32) bias_s[tid] = bias[tid];
    __syncthreads();

    const int lane = tid & 63;
    const int hi   = lane >> 5;
    const int l31  = lane & 31;
    const int w    = tid >> 6;

    #pragma unroll 1
    for (int s = 0; s < 2; ++s) {
        const int n = blockIdx.x * 8 + 2 * w + s;   // exact: gridDim.x = NN/8

        const int deg = cnt[n];
        const int2* bk = bucket + (size_t)n * CAP;

        float msgr[16];
        #pragma unroll
        for (int r = 0; r < 16; ++r) msgr[r] = 0.0f;

        for (int c0 = 0; c0 < deg; c0 += 32) {
            const int idx  = c0 + l31;
            const bool act = idx < deg;
            const int2 es  = bk[act ? idx : deg - 1];   // {e, src}, clamped

            const f32x4* eap = (const f32x4*)(ea + (size_t)es.x * 16 + hi * 8);
            f32x4 f0 = eap[0];
            f32x4 f1 = eap[1];
            bf16x8 bfrag;
            bfrag[0]=(__bf16)f0.x; bfrag[1]=(__bf16)f0.y; bfrag[2]=(__bf16)f0.z; bfrag[3]=(__bf16)f0.w;
            bfrag[4]=(__bf16)f1.x; bfrag[5]=(__bf16)f1.y; bfrag[6]=(__bf16)f1.z; bfrag[7]=(__bf16)f1.w;

            const float4* xp = (const float4*)(x + (size_t)es.y * 32);

            // opaque base: defeats LICM/CSE of the af/ci reads across chunks.
            int base = 0;
            asm volatile("" : "+v"(base));

            #pragma unroll
            for (int cbq = 0; cbq < 8; ++cbq) {
                float4 xq = xp[cbq];
                if (!act) { xq.x = 0.f; xq.y = 0.f; xq.z = 0.f; xq.w = 0.f; }
                #pragma unroll
                for (int c4 = 0; c4 < 4; ++c4) {
                    const int g = cbq * 4 + c4;
                    bf16x8 af = *(const bf16x8*)(&WT[base + g][hi][l31][0]);
                    f32x16 ci = *(const f32x16*)(&BPF[base + g][hi][0]);
                    f32x16 acc = __builtin_amdgcn_mfma_f32_32x32x16_bf16(af, bfrag, ci, 0, 0, 0);
                    const float xv = (c4 == 0) ? xq.x : (c4 == 1) ? xq.y : (c4 == 2) ? xq.z : xq.w;
                    #pragma unroll
                    for (int r = 0; r < 16; ++r)
                        msgr[r] += fmaxf(acc[r], 0.0f) * xv;
                    if (c4 & 1) __builtin_amdgcn_sched_barrier(0);  // 2-group window
                }
            }
        }

        // reduce across the 32 slot-lanes within each hi-half
        #pragma unroll
        for (int m = 1; m <= 16; m <<= 1) {
            #pragma unroll
            for (int r = 0; r < 16; ++r)
                msgr[r] += __shfl_xor(msgr[r], m, 64);
        }

        const float rdeg = (deg > 0) ? (1.0f / (float)deg) : 0.0f;
        if (l31 == 0) {
            #pragma unroll
            for (int r = 0; r < 16; ++r) {
                const int o = (r & 3) + 8 * (r >> 2) + 4 * hi;
                msum[2 * w + s][o] = msgr[r] * rdeg;
            }
        }
    }
    __syncthreads();

    // epilogue: 8 rows x 32 ch; row r <-> node blk*8 + r <-> msum[r]
    {
        const int row = tid >> 5, o = tid & 31;
        const int nn  = blockIdx.x * 8 + row;
        const float xv = x[(size_t)nn * 32 + o];   // lane o holds x[nn][o]
        float m = msum[row][o] + bias_s[o];
        #pragma unroll
        for (int i = 0; i < 32; ++i)
            m += __shfl(xv, i, 32) * root_s[i][o];
        out[(size_t)nn * 32 + o] = m;
    }
}

// ======================= launch =======================
extern "C" void kernel_launch(void* const* d_in, const int* in_sizes, int n_in,
                              void* d_out, int out_size, void* d_ws, size_t ws_size,
                              hipStream_t stream) {
    const float* x    = (const float*)d_in[0];
    const int*   eidx = (const int*)d_in[1];     // [2][NE]
    const float* ea   = (const float*)d_in[2];   // [NE][16]
    const float* W    = (const float*)d_in[3];   // [16][1024]
    const float* be   = (const float*)d_in[4];   // [1024]
    const float* root = (const float*)d_in[5];   // [32][32]
    const float* bias = (const float*)d_in[6];   // [32]
    float* out = (float*)d_out;

    // ws: cnt[NN] ints | bucket int2[NN*CAP]
    int*  cnt    = (int*)d_ws;
    int2* bucket = (int2*)((char*)d_ws + ((NN * 4 + 15) & ~15));

    hipMemsetAsync(cnt, 0, NN * sizeof(int), stream);
    scatter_bucket_kernel<<<640, 256, 0, stream>>>(eidx, cnt, bucket);
    edge_node_kernel<<<NN / 8, 256, 0, stream>>>(x, ea, W, be, root, bias,
                                                 cnt, bucket, out);
}